// Round 4
// baseline (277.453 us; speedup 1.0000x reference)
//
#include <hip/hip_runtime.h>
#include <hip/hip_bf16.h>
#include <stdint.h>

// HyperbolicAttention MI355X implementation.
// B=2, N=4096, D_IN=256, UNITS=512, H=8, depth=64.
// Round 4: round-3 design (barrier-free attention, Q register-resident, K/V streamed
// global->reg, wave-private LDS P-transpose, zero-padded K=32 PV MFMA, exp2 folding,
// cvt_pk bf16 packing) with the vector-element-address compile error fixed.

typedef __attribute__((ext_vector_type(8))) short short8;
typedef __attribute__((ext_vector_type(4))) short short4v;
typedef __attribute__((ext_vector_type(4))) float f32x4;
typedef __attribute__((ext_vector_type(2))) unsigned int u32x2;
typedef __attribute__((ext_vector_type(4))) unsigned int u32x4;

#define DEVFN static __device__ __forceinline__

DEVFN unsigned short f2bf(float f) {
  unsigned u = __float_as_uint(f);
  u += 0x7FFFu + ((u >> 16) & 1u);   // RNE
  return (unsigned short)(u >> 16);
}

// Builtin MFMA: compiler-visible (hazard + scheduling safe).
DEVFN void mfma16(f32x4& d, short8 a, short8 b) {
  d = __builtin_amdgcn_mfma_f32_16x16x32_bf16(a, b, d, 0, 0, 0);
}

DEVFN void gload_lds16(const void* g, void* l) {
  __builtin_amdgcn_global_load_lds((__attribute__((address_space(1))) void*)g,
                                   (__attribute__((address_space(3))) void*)l, 16, 0, 0);
}

// ---------------- weight convert + transpose to BT layout (bf16) ----------------
__global__ __launch_bounds__(256) void wconv_kernel(const float* Wq, const float* Wk,
                                                    const float* Wv, const float* Wo,
                                                    unsigned short* wqkvT, unsigned short* woT) {
  int t = blockIdx.x * 256 + threadIdx.x;
  if (t < 1536 * 256) {
    int nn = t >> 8, kk = t & 255;       // wqkvT[nn][kk] = W[kk][nn%512] of (q,k,v)
    int which = nn >> 9, n2 = nn & 511;
    const float* W = (which == 0) ? Wq : (which == 1) ? Wk : Wv;
    wqkvT[t] = f2bf(W[kk * 512 + n2]);
  }
  int t2 = t - 1536 * 256;
  if (t2 >= 0 && t2 < 512 * 512) {
    int nn = t2 >> 9, kk = t2 & 511;
    woT[t2] = f2bf(Wo[kk * 512 + nn]);
  }
}

// ---------------- tangent = logmap0(inputs), bf16 [8192][256] ----------------
__global__ __launch_bounds__(256) void tangent_kernel(const float* x, unsigned short* tang) {
  const int row = blockIdx.x;
  const int tid = threadIdx.x;
  float v = x[(size_t)row * 256 + tid];
  float ss = v * v;
  #pragma unroll
  for (int m = 1; m <= 32; m <<= 1) ss += __shfl_xor(ss, m, 64);
  __shared__ __align__(16) float red[4];
  if ((tid & 63) == 0) red[tid >> 6] = ss;
  __syncthreads();
  float tot = (red[0] + red[1]) + (red[2] + red[3]);
  float n = fmaxf(sqrtf(tot), 1e-7f);
  float arg = fminf(n, 1.0f - 1e-5f);
  float scale = atanhf(arg) / n;
  tang[(size_t)row * 256 + tid] = f2bf(v * scale);
}

// ---------------- GEMM: C[M][N] f32 = A[M][K]bf16 @ B, B given as BT[N][K]bf16 ----------------
__global__ __launch_bounds__(256) void gemm_bt(const unsigned short* A, const unsigned short* BT,
                                               float* C, int M, int N, int K, int NB) {
  __shared__ __align__(16) unsigned short As[2][64 * 64];
  __shared__ __align__(16) unsigned short Bs[2][64 * 64];
  const int tid = threadIdx.x;
  const int l = tid & 63, w = tid >> 6;
  const int g = l >> 4, i = l & 15;
  const int bm = blockIdx.x / NB, bn = blockIdx.x % NB;
  const int m0 = bm << 6, n0 = bn << 6;
  const int wm = w >> 1, wn = w & 1;
  f32x4 acc[2][2] = {};

  const int NK = K >> 6;
  auto stage = [&](int kc, int bb) {
    const int kb = kc << 6;
    #pragma unroll
    for (int inst = 0; inst < 2; ++inst) {
      int o = (w << 11) + (inst << 10) + (l << 4);
      int row = o >> 7;
      int gG = ((o >> 4) & 7) ^ (row & 7);
      gload_lds16(A + ((size_t)(m0 + row) * K + kb + gG * 8),
                  (char*)&As[bb][0] + (w << 11) + (inst << 10));
      gload_lds16(BT + ((size_t)(n0 + row) * K + kb + gG * 8),
                  (char*)&Bs[bb][0] + (w << 11) + (inst << 10));
    }
  };
  stage(0, 0);
  __syncthreads();
  for (int kc = 0; kc < NK; ++kc) {
    const int bb = kc & 1;
    if (kc + 1 < NK) stage(kc + 1, bb ^ 1);
    #pragma unroll
    for (int hh = 0; hh < 2; ++hh) {
      short8 af[2], bf[2];
      #pragma unroll
      for (int mt = 0; mt < 2; ++mt) {
        int row = (wm << 5) + (mt << 4) + i;
        af[mt] = *(const short8*)((const char*)&As[bb][0] + (row << 7) +
                                  ((((hh << 2) + g) ^ (row & 7)) << 4));
      }
      #pragma unroll
      for (int nt = 0; nt < 2; ++nt) {
        int row = (wn << 5) + (nt << 4) + i;
        bf[nt] = *(const short8*)((const char*)&Bs[bb][0] + (row << 7) +
                                  ((((hh << 2) + g) ^ (row & 7)) << 4));
      }
      #pragma unroll
      for (int mt = 0; mt < 2; ++mt)
        #pragma unroll
        for (int nt = 0; nt < 2; ++nt)
          mfma16(acc[mt][nt], af[mt], bf[nt]);
    }
    __syncthreads();
  }
  #pragma unroll
  for (int mt = 0; mt < 2; ++mt)
    #pragma unroll
    for (int nt = 0; nt < 2; ++nt)
      #pragma unroll
      for (int r = 0; r < 4; ++r) {
        int row = m0 + (wm << 5) + (mt << 4) + (g << 2) + r;
        int col = n0 + (wn << 5) + (nt << 4) + i;
        C[(size_t)row * N + col] = acc[mt][nt][r];
      }
}

// ---------------- per-head hyperbolic maps ----------------
// qkv f32 [8192][1536] -> qh,kh bf16 [8192][512]; k2lT f32 [16][4096] = ||k_hyp||^2/8*log2(e);
// vT bf16 [16][64][4096] = logmap0(v) transposed per head.
__global__ __launch_bounds__(256) void hyp_kernel(const float* qkv, unsigned short* qh,
                                                  unsigned short* kh, unsigned short* vT,
                                                  float* k2lT) {
  __shared__ __align__(16) unsigned short vt_t[64][72];
  const int tid = threadIdx.x;
  const int l = tid & 63, w = tid >> 6;
  const int bh = blockIdx.x & 15, nt = blockIdx.x >> 4;
  const int b = bh >> 3, h = bh & 7;
  const int n0 = nt << 6;
  const int d = l;
  for (int r = 0; r < 16; ++r) {
    int n = n0 + w * 16 + r;
    size_t base = (size_t)(b * 4096 + n) * 1536 + h * 64 + d;
    float qv = qkv[base], kv = qkv[base + 512], vv = qkv[base + 1024];
    float sq = qv * qv, sk = kv * kv, sv = vv * vv;
    #pragma unroll
    for (int m = 1; m <= 32; m <<= 1) {
      sq += __shfl_xor(sq, m, 64);
      sk += __shfl_xor(sk, m, 64);
      sv += __shfl_xor(sv, m, 64);
    }
    float nq = fmaxf(sqrtf(sq), 1e-7f);
    float qs = tanhf(nq) / nq;
    float nk = fmaxf(sqrtf(sk), 1e-7f);
    float tk = tanhf(nk);
    float ks = tk / nk;
    float nv = fmaxf(sqrtf(sv), 1e-7f);
    float vs = atanhf(fminf(nv, 1.0f - 1e-5f)) / nv;
    size_t ob = (size_t)(b * 4096 + n) * 512 + h * 64 + d;
    qh[ob] = f2bf(qv * qs);
    kh[ob] = f2bf(kv * ks);
    if (d == 0) k2lT[(size_t)bh * 4096 + n] = tk * tk * 0.125f * 1.4426950408889634f;
    vt_t[d][w * 16 + r] = f2bf(vv * vs);
  }
  __syncthreads();
  const int dd = tid >> 2, p = tid & 3;
  u32x4 a0 = *(const u32x4*)&vt_t[dd][p * 16];
  u32x4 a1 = *(const u32x4*)&vt_t[dd][p * 16 + 8];
  size_t vb = (size_t)(bh * 64 + dd) * 4096 + n0 + p * 16;
  *(u32x4*)(vT + vb) = a0;
  *(u32x4*)(vT + vb + 8) = a1;
}

// ---------------- attention (barrier-free main loop) ----------------
// Grid 1024 = (bh, 64 q-rows). 4 waves; wave w owns j-slice [jc*64 + w*16, +16) per jc.
// Q register-resident (64q x 64d per block). K/V/k2 streamed global->reg (L2-resident,
// XCD-swizzled so each XCD serves 2 bh). Swapped QK: S^T = mfma(K,Q) -> C rows are j.
// P goes through a wave-private LDS buffer [64 q][16 j | 16 zero cols] so the PV
// B-fragment (k = j, zero-padded to K=32) is a single b128 read. Denominator =
// mfma(ONES, P): identical path to numerator; cross-wave reduced with the output.
__global__ __launch_bounds__(256, 2) void attn_kernel(const unsigned short* __restrict__ qhG,
                                                      const unsigned short* __restrict__ khG,
                                                      const unsigned short* __restrict__ vTG,
                                                      const float* __restrict__ k2lG,
                                                      unsigned short* __restrict__ ctx) {
  // smem: [0,20480): per-wave P buffers [64][40] bf16 (main loop only)
  //       after barrier: red f32 [4][64][68] (69632 B) + redden f32 [4][64] (1024 B)
  __shared__ __align__(16) char smem[70656];
  const int tid = threadIdx.x;
  const int l = tid & 63, w = tid >> 6;
  const int g = l >> 4, i = l & 15;
  // XCD swizzle: xcd = p&7 gets bh {2*xcd, 2*xcd+1} -> ~3MB working set per XCD L2.
  const int p = blockIdx.x;
  const int bh = ((p & 7) << 1) + ((p >> 3) & 1);
  const int qt0 = p >> 4;                 // 0..63
  const int b = bh >> 3, h = bh & 7;
  const int q0 = qt0 << 6;

  char* pbB = smem + w * 5120;            // wave-private [64 rows][80 B]
  {                                        // zero j-local cols 16..31 (bytes 32..63)
    u32x4 z = {0, 0, 0, 0};
    *(u32x4*)(pbB + l * 80 + 32) = z;
    *(u32x4*)(pbB + l * 80 + 48) = z;
  }

  // resident Q fragments: B-frag of QK mfma. qf[qt][hh]
  short8 qf[4][2];
  #pragma unroll
  for (int qt = 0; qt < 4; ++qt)
    #pragma unroll
    for (int hh = 0; hh < 2; ++hh)
      qf[qt][hh] = *(const short8*)(qhG + (size_t)(b * 4096 + q0 + qt * 16 + i) * 512 +
                                    h * 64 + hh * 32 + g * 8);

  f32x4 acc[4][4] = {};    // [dt][qt]  O^T partial: rows d=dt*16+g*4+r, col q=qt*16+i
  f32x4 accden[4] = {};    // [qt]      denominator partial (all rows equal)

  const unsigned short* Kp = khG + (size_t)(b * 4096 + w * 16 + i) * 512 + h * 64 + g * 8;
  const unsigned short* Vp = vTG + (size_t)(bh * 64 + i) * 4096 + w * 16 + (g & 1) * 8;
  const float* k2p = k2lG + (size_t)bh * 4096 + w * 16 + g * 4;
  const short8 ONES = {16256, 16256, 16256, 16256, 16256, 16256, 16256, 16256};
  const float CQK = 0.36067376022224087f;  // 0.25 * log2(e)

  auto LDK = [&](int jc, short8& a, short8& b2) {
    const unsigned short* q = Kp + (size_t)jc * (64 * 512);
    a = *(const short8*)q;
    b2 = *(const short8*)(q + 32);
  };
  auto LDV = [&](int jc, short8 (&v)[4]) {
    const unsigned short* q = Vp + jc * 64;
    #pragma unroll
    for (int dt = 0; dt < 4; ++dt) v[dt] = *(const short8*)(q + dt * 16 * 4096);
  };
  auto LD2 = [&](int jc, f32x4& c) { c = *(const f32x4*)(k2p + jc * 64); };

  auto STEP = [&](short8 k0, short8 k1, short8 (&vf)[4], f32x4 k2v) {
    // phase 1: QK^T -> p -> bf16 pack -> LDS (wave-private)
    #pragma unroll
    for (int qt = 0; qt < 4; ++qt) {
      f32x4 S = {0.f, 0.f, 0.f, 0.f};
      mfma16(S, k0, qf[qt][0]);
      mfma16(S, k1, qf[qt][1]);
      f32x4 pr;
      #pragma unroll
      for (int r = 0; r < 4; ++r)
        pr[r] = __builtin_amdgcn_exp2f(fmaf(S[r], CQK, -k2v[r]));
      __hip_bfloat162 lo = __float22bfloat162_rn(make_float2(pr[0], pr[1]));
      __hip_bfloat162 hi = __float22bfloat162_rn(make_float2(pr[2], pr[3]));
      unsigned lo_u, hi_u;
      __builtin_memcpy(&lo_u, &lo, 4);
      __builtin_memcpy(&hi_u, &hi, 4);
      u32x2 pk;
      pk[0] = lo_u;
      pk[1] = hi_u;
      *(u32x2*)(pbB + (qt * 16 + i) * 80 + g * 8) = pk;   // rows q, cols j-local g*4..+3
    }
    // phase 2: PV + denominator
    #pragma unroll
    for (int qt = 0; qt < 4; ++qt) {
      short8 pf = *(const short8*)(pbB + (qt * 16 + i) * 80 + g * 16);  // k>=16 reads zeros
      mfma16(accden[qt], ONES, pf);
      #pragma unroll
      for (int dt = 0; dt < 4; ++dt)
        mfma16(acc[dt][qt], vf[dt], pf);
    }
  };

  short8 kA0, kA1, kB0, kB1, vA[4], vB[4];
  f32x4 cA, cB;
  LDK(0, kA0, kA1); LDV(0, vA); LD2(0, cA);
  for (int jc = 0; jc < 64; jc += 2) {
    LDK(jc + 1, kB0, kB1); LDV(jc + 1, vB); LD2(jc + 1, cB);
    STEP(kA0, kA1, vA, cA);
    if (jc + 2 < 64) { LDK(jc + 2, kA0, kA1); LDV(jc + 2, vA); LD2(jc + 2, cA); }
    STEP(kB0, kB1, vB, cB);
  }

  // cross-wave reduction (Pbuf dead; red region aliases it)
  __syncthreads();
  float (*red)[64][68] = (float (*)[64][68])smem;
  float (*redden)[64] = (float (*)[64])(smem + 69632);
  #pragma unroll
  for (int dt = 0; dt < 4; ++dt)
    #pragma unroll
    for (int qt = 0; qt < 4; ++qt)
      #pragma unroll
      for (int r = 0; r < 4; ++r)
        red[w][dt * 16 + (g << 2) + r][qt * 16 + i] = acc[dt][qt][r];
  if (g == 0) {
    #pragma unroll
    for (int qt = 0; qt < 4; ++qt) redden[w][qt * 16 + i] = accden[qt][0];
  }
  __syncthreads();

  const int q = tid >> 2, dblk = tid & 3;
  float den = (redden[0][q] + redden[1][q]) + (redden[2][q] + redden[3][q]);
  float inv = 1.0f / den;
  u32x4 o0, o1;
  #pragma unroll
  for (int j = 0; j < 4; ++j) {
    int d0 = dblk * 16 + j * 2;
    float s0 = ((red[0][d0][q] + red[1][d0][q]) + (red[2][d0][q] + red[3][d0][q])) * inv;
    float s1 = ((red[0][d0 + 1][q] + red[1][d0 + 1][q]) +
                (red[2][d0 + 1][q] + red[3][d0 + 1][q])) * inv;
    o0[j] = (unsigned)f2bf(s0) | ((unsigned)f2bf(s1) << 16);
  }
  #pragma unroll
  for (int j = 0; j < 4; ++j) {
    int d0 = dblk * 16 + 8 + j * 2;
    float s0 = ((red[0][d0][q] + red[1][d0][q]) + (red[2][d0][q] + red[3][d0][q])) * inv;
    float s1 = ((red[0][d0 + 1][q] + red[1][d0 + 1][q]) +
                (red[2][d0 + 1][q] + red[3][d0 + 1][q])) * inv;
    o1[j] = (unsigned)f2bf(s0) | ((unsigned)f2bf(s1) << 16);
  }
  unsigned short* dst = ctx + (size_t)(b * 4096 + q0 + q) * 512 + h * 64 + dblk * 16;
  *(u32x4*)dst = o0;
  *(u32x4*)(dst + 8) = o1;
}

// ---------------- final expmap0 over 512-dim rows ----------------
__global__ __launch_bounds__(256) void final_kernel(const float* xin, float* out) {
  const int row = blockIdx.x;
  const int tid = threadIdx.x;
  const float* xr = xin + (size_t)row * 512;
  float v0 = xr[tid], v1 = xr[tid + 256];
  float ss = v0 * v0 + v1 * v1;
  #pragma unroll
  for (int m = 1; m <= 32; m <<= 1) ss += __shfl_xor(ss, m, 64);
  __shared__ __align__(16) float red[4];
  if ((tid & 63) == 0) red[tid >> 6] = ss;
  __syncthreads();
  float tot = (red[0] + red[1]) + (red[2] + red[3]);
  float n = fmaxf(sqrtf(tot), 1e-7f);
  float sc = tanhf(n) / n;
  out[(size_t)row * 512 + tid] = v0 * sc;
  out[(size_t)row * 512 + tid + 256] = v1 * sc;
}

// ---------------- launch ----------------
extern "C" void kernel_launch(void* const* d_in, const int* in_sizes, int n_in,
                              void* d_out, int out_size, void* d_ws, size_t ws_size,
                              hipStream_t stream) {
  const float* inputs = (const float*)d_in[0];
  const float* Wq = (const float*)d_in[1];
  const float* Wk = (const float*)d_in[2];
  const float* Wv = (const float*)d_in[3];
  const float* Wo = (const float*)d_in[4];
  float* out = (float*)d_out;
  char* ws = (char*)d_ws;

  // workspace layout (~79.25 MB peak):
  //  [0,48M):  qkv f32 [8192][1536]  -- reused after hyp: ctx bf16 @0 (8M), out_pre f32 @8M (16M)
  //  [48M):    tangent bf16 (4M)     -- reused after proj: k2lT f32 (256K)
  //  [53M): wqkvT bf16 (0.75M); [54M): woT bf16 (0.5M)
  //  [55M): qh bf16 (8M); [63M): kh bf16 (8M); [71M): vT bf16 (8M)
  float* qkv            = (float*)(ws);
  unsigned short* ctx   = (unsigned short*)(ws);
  float* out_pre        = (float*)(ws + ((size_t)8 << 20));
  unsigned short* tang  = (unsigned short*)(ws + ((size_t)48 << 20));
  float* k2lT           = (float*)(ws + ((size_t)48 << 20));
  unsigned short* wqkvT = (unsigned short*)(ws + ((size_t)53 << 20));
  unsigned short* woT   = (unsigned short*)(ws + ((size_t)54 << 20));
  unsigned short* qh    = (unsigned short*)(ws + ((size_t)55 << 20));
  unsigned short* kh    = (unsigned short*)(ws + ((size_t)63 << 20));
  unsigned short* vT    = (unsigned short*)(ws + ((size_t)71 << 20));

  wconv_kernel<<<2560, 256, 0, stream>>>(Wq, Wk, Wv, Wo, wqkvT, woT);
  tangent_kernel<<<8192, 256, 0, stream>>>(inputs, tang);
  gemm_bt<<<128 * 24, 256, 0, stream>>>(tang, wqkvT, qkv, 8192, 1536, 256, 24);
  hyp_kernel<<<1024, 256, 0, stream>>>(qkv, qh, kh, vT, k2lT);
  attn_kernel<<<1024, 256, 0, stream>>>(qh, kh, vT, k2lT, ctx);
  gemm_bt<<<128 * 8, 256, 0, stream>>>(ctx, woT, out_pre, 8192, 512, 512, 8);
  final_kernel<<<8192, 256, 0, stream>>>(out_pre, out);
}

// Round 5
// 190.771 us; speedup vs baseline: 1.4544x; 1.4544x over previous
//
#include <hip/hip_runtime.h>
#include <hip/hip_bf16.h>
#include <stdint.h>

// HyperbolicAttention MI355X implementation.
// B=2, N=4096, D_IN=256, UNITS=512, H=8, depth=64.
// Round 5: round-2 attention structure (cross-wave K/V staging, per-wave q-strips)
// with 8 waves/block (2x occupancy), exp2 folding, and cvt_pk bf16 packing.

typedef __attribute__((ext_vector_type(8))) short short8;
typedef __attribute__((ext_vector_type(4))) short short4v;
typedef __attribute__((ext_vector_type(4))) float f32x4;
typedef __attribute__((ext_vector_type(2))) unsigned int u32x2;
typedef __attribute__((ext_vector_type(4))) unsigned int u32x4;

#define DEVFN static __device__ __forceinline__

DEVFN unsigned short f2bf(float f) {
  unsigned u = __float_as_uint(f);
  u += 0x7FFFu + ((u >> 16) & 1u);   // RNE
  return (unsigned short)(u >> 16);
}

// Builtin MFMA: compiler-visible (hazard + scheduling safe).
DEVFN void mfma16(f32x4& d, short8 a, short8 b) {
  d = __builtin_amdgcn_mfma_f32_16x16x32_bf16(a, b, d, 0, 0, 0);
}

DEVFN void gload_lds16(const void* g, void* l) {
  __builtin_amdgcn_global_load_lds((__attribute__((address_space(1))) void*)g,
                                   (__attribute__((address_space(3))) void*)l, 16, 0, 0);
}
DEVFN void gload_lds4(const void* g, void* l) {
  __builtin_amdgcn_global_load_lds((__attribute__((address_space(1))) void*)g,
                                   (__attribute__((address_space(3))) void*)l, 4, 0, 0);
}

// ---------------- weight convert + transpose to BT layout (bf16) ----------------
__global__ __launch_bounds__(256) void wconv_kernel(const float* Wq, const float* Wk,
                                                    const float* Wv, const float* Wo,
                                                    unsigned short* wqkvT, unsigned short* woT) {
  int t = blockIdx.x * 256 + threadIdx.x;
  if (t < 1536 * 256) {
    int nn = t >> 8, kk = t & 255;       // wqkvT[nn][kk] = W[kk][nn%512] of (q,k,v)
    int which = nn >> 9, n2 = nn & 511;
    const float* W = (which == 0) ? Wq : (which == 1) ? Wk : Wv;
    wqkvT[t] = f2bf(W[kk * 512 + n2]);
  }
  int t2 = t - 1536 * 256;
  if (t2 >= 0 && t2 < 512 * 512) {
    int nn = t2 >> 9, kk = t2 & 511;
    woT[t2] = f2bf(Wo[kk * 512 + nn]);
  }
}

// ---------------- tangent = logmap0(inputs), bf16 [8192][256] ----------------
__global__ __launch_bounds__(256) void tangent_kernel(const float* x, unsigned short* tang) {
  const int row = blockIdx.x;
  const int tid = threadIdx.x;
  float v = x[(size_t)row * 256 + tid];
  float ss = v * v;
  #pragma unroll
  for (int m = 1; m <= 32; m <<= 1) ss += __shfl_xor(ss, m, 64);
  __shared__ __align__(16) float red[4];
  if ((tid & 63) == 0) red[tid >> 6] = ss;
  __syncthreads();
  float tot = (red[0] + red[1]) + (red[2] + red[3]);
  float n = fmaxf(sqrtf(tot), 1e-7f);
  float arg = fminf(n, 1.0f - 1e-5f);
  float scale = atanhf(arg) / n;
  tang[(size_t)row * 256 + tid] = f2bf(v * scale);
}

// ---------------- GEMM: C[M][N] f32 = A[M][K]bf16 @ B, B given as BT[N][K]bf16 ----------------
__global__ __launch_bounds__(256) void gemm_bt(const unsigned short* A, const unsigned short* BT,
                                               float* C, int M, int N, int K, int NB) {
  __shared__ __align__(16) unsigned short As[2][64 * 64];
  __shared__ __align__(16) unsigned short Bs[2][64 * 64];
  const int tid = threadIdx.x;
  const int l = tid & 63, w = tid >> 6;
  const int g = l >> 4, i = l & 15;
  const int bm = blockIdx.x / NB, bn = blockIdx.x % NB;
  const int m0 = bm << 6, n0 = bn << 6;
  const int wm = w >> 1, wn = w & 1;
  f32x4 acc[2][2] = {};

  const int NK = K >> 6;
  auto stage = [&](int kc, int bb) {
    const int kb = kc << 6;
    #pragma unroll
    for (int inst = 0; inst < 2; ++inst) {
      int o = (w << 11) + (inst << 10) + (l << 4);
      int row = o >> 7;
      int gG = ((o >> 4) & 7) ^ (row & 7);
      gload_lds16(A + ((size_t)(m0 + row) * K + kb + gG * 8),
                  (char*)&As[bb][0] + (w << 11) + (inst << 10));
      gload_lds16(BT + ((size_t)(n0 + row) * K + kb + gG * 8),
                  (char*)&Bs[bb][0] + (w << 11) + (inst << 10));
    }
  };
  stage(0, 0);
  __syncthreads();
  for (int kc = 0; kc < NK; ++kc) {
    const int bb = kc & 1;
    if (kc + 1 < NK) stage(kc + 1, bb ^ 1);
    #pragma unroll
    for (int hh = 0; hh < 2; ++hh) {
      short8 af[2], bf[2];
      #pragma unroll
      for (int mt = 0; mt < 2; ++mt) {
        int row = (wm << 5) + (mt << 4) + i;
        af[mt] = *(const short8*)((const char*)&As[bb][0] + (row << 7) +
                                  ((((hh << 2) + g) ^ (row & 7)) << 4));
      }
      #pragma unroll
      for (int nt = 0; nt < 2; ++nt) {
        int row = (wn << 5) + (nt << 4) + i;
        bf[nt] = *(const short8*)((const char*)&Bs[bb][0] + (row << 7) +
                                  ((((hh << 2) + g) ^ (row & 7)) << 4));
      }
      #pragma unroll
      for (int mt = 0; mt < 2; ++mt)
        #pragma unroll
        for (int nt = 0; nt < 2; ++nt)
          mfma16(acc[mt][nt], af[mt], bf[nt]);
    }
    __syncthreads();
  }
  #pragma unroll
  for (int mt = 0; mt < 2; ++mt)
    #pragma unroll
    for (int nt = 0; nt < 2; ++nt)
      #pragma unroll
      for (int r = 0; r < 4; ++r) {
        int row = m0 + (wm << 5) + (mt << 4) + (g << 2) + r;
        int col = n0 + (wn << 5) + (nt << 4) + i;
        C[(size_t)row * N + col] = acc[mt][nt][r];
      }
}

// ---------------- per-head hyperbolic maps ----------------
// qkv f32 [8192][1536] -> qh,kh bf16 [8192][512]; k2lT f32 [16][4096] = ||k_hyp||^2/8*log2(e);
// vT bf16 [16][64][4096] = logmap0(v) transposed per head.
__global__ __launch_bounds__(256) void hyp_kernel(const float* qkv, unsigned short* qh,
                                                  unsigned short* kh, unsigned short* vT,
                                                  float* k2lT) {
  __shared__ __align__(16) unsigned short vt_t[64][72];
  const int tid = threadIdx.x;
  const int l = tid & 63, w = tid >> 6;
  const int bh = blockIdx.x & 15, nt = blockIdx.x >> 4;
  const int b = bh >> 3, h = bh & 7;
  const int n0 = nt << 6;
  const int d = l;
  for (int r = 0; r < 16; ++r) {
    int n = n0 + w * 16 + r;
    size_t base = (size_t)(b * 4096 + n) * 1536 + h * 64 + d;
    float qv = qkv[base], kv = qkv[base + 512], vv = qkv[base + 1024];
    float sq = qv * qv, sk = kv * kv, sv = vv * vv;
    #pragma unroll
    for (int m = 1; m <= 32; m <<= 1) {
      sq += __shfl_xor(sq, m, 64);
      sk += __shfl_xor(sk, m, 64);
      sv += __shfl_xor(sv, m, 64);
    }
    float nq = fmaxf(sqrtf(sq), 1e-7f);
    float qs = tanhf(nq) / nq;
    float nk = fmaxf(sqrtf(sk), 1e-7f);
    float tk = tanhf(nk);
    float ks = tk / nk;
    float nv = fmaxf(sqrtf(sv), 1e-7f);
    float vs = atanhf(fminf(nv, 1.0f - 1e-5f)) / nv;
    size_t ob = (size_t)(b * 4096 + n) * 512 + h * 64 + d;
    qh[ob] = f2bf(qv * qs);
    kh[ob] = f2bf(kv * ks);
    if (d == 0) k2lT[(size_t)bh * 4096 + n] = tk * tk * 0.125f * 1.4426950408889634f;
    vt_t[d][w * 16 + r] = f2bf(vv * vs);
  }
  __syncthreads();
  const int dd = tid >> 2, p = tid & 3;
  u32x4 a0 = *(const u32x4*)&vt_t[dd][p * 16];
  u32x4 a1 = *(const u32x4*)&vt_t[dd][p * 16 + 8];
  size_t vb = (size_t)(bh * 64 + dd) * 4096 + n0 + p * 16;
  *(u32x4*)(vT + vb) = a0;
  *(u32x4*)(vT + vb + 8) = a1;
}

// ---------------- attention ----------------
// Grid 512 = (bh, 128 q-rows), 512 threads = 8 waves; wave w owns q-strip
// [qt*128 + w*16, +16). K/V/k2 staged global->LDS (double-buffered, all waves share).
// Logits*log2e = S*CQK - k2l (q2 cancels in softmax; logits bounded -> no max needed).
// Swapped QK^T: S^T = mfma(K, Q) -> C rows are j, cols are q. P transposed to the PV
// A-layout via a wave-private LDS buffer. Denominator = mfma(P, ONES): structurally
// identical path to the numerator -> exact normalization by construction.
__global__ __launch_bounds__(512) void attn_kernel(const unsigned short* __restrict__ qhG,
                                                   const unsigned short* __restrict__ khG,
                                                   const unsigned short* __restrict__ vTG,
                                                   const float* __restrict__ k2lG,
                                                   unsigned short* __restrict__ ctx) {
  __shared__ __align__(16) unsigned short Kbuf[2][64 * 64];
  __shared__ __align__(16) unsigned short Vbuf[2][64 * 64];
  __shared__ __align__(16) float k2buf[2][64];
  __shared__ __align__(16) unsigned short Pbuf[8][16 * 40];  // [wave][16 q rows][32+8 pad]

  const int tid = threadIdx.x;
  const int l = tid & 63, w = tid >> 6;
  const int g = l >> 4, i = l & 15;
  const int bh = blockIdx.x & 15, qt = blockIdx.x >> 4;   // same-bh blocks share an XCD L2
  const int b = bh >> 3, h = bh & 7;
  const int qbase = qt * 128 + w * 16;

  const short8 ONES = {16256, 16256, 16256, 16256, 16256, 16256, 16256, 16256};  // bf16 1.0
  const float CQK = 0.36067376022224087f;  // 0.25 * log2(e)

  // resident Q fragments (B-frag of swapped QK mfma): rows q = i, k-group g.
  short8 qf[2];
  #pragma unroll
  for (int hh = 0; hh < 2; ++hh)
    qf[hh] = *(const short8*)(qhG + (size_t)(b * 4096 + qbase + i) * 512 +
                              h * 64 + hh * 32 + g * 8);

  f32x4 acc[4] = {};     // [ds]: D[q][d] tile, row q = g*4+r, col d = ds*16+i
  f32x4 accden = {};     // rowsum via ones-MFMA, same row map

  char* Pw = (char*)&Pbuf[w][0];

  auto stage = [&](int jc, int bb) {
    const int jb = jc << 6;
    const int o = tid << 4;            // 0..8191: one 16B inst per thread
    const int row = o >> 7;            // 0..63
    const int gG = ((o >> 4) & 7) ^ (row & 7);
    gload_lds16(khG + ((size_t)(b * 4096 + jb + row) * 512 + h * 64 + gG * 8),
                (char*)&Kbuf[bb][0] + o);
    gload_lds16(vTG + ((size_t)(bh * 64 + row) * 4096 + jb + gG * 8),
                (char*)&Vbuf[bb][0] + o);
    if (tid < 64) gload_lds4(k2lG + (size_t)bh * 4096 + jb + tid, (char*)&k2buf[bb][0]);
  };

  stage(0, 0);
  __syncthreads();

  for (int jc = 0; jc < 64; ++jc) {
    const int bb = jc & 1;
    if (jc + 1 < 64) stage(jc + 1, bb ^ 1);
    const char* Kb = (const char*)&Kbuf[bb][0];
    const char* Vb = (const char*)&Vbuf[bb][0];

    #pragma unroll
    for (int u = 0; u < 2; ++u) {          // 32-j sub-chunk
      #pragma unroll
      for (int t = 0; t < 2; ++t) {        // 16-j tile
        const int jt = u * 2 + t;
        const int krow = jt * 16 + i;
        const int sw = (krow & 7) << 4;
        short8 kf0 = *(const short8*)(Kb + (krow << 7) + ((g << 4) ^ sw));
        short8 kf1 = *(const short8*)(Kb + (krow << 7) + (((g + 4) << 4) ^ sw));
        f32x4 S = {0.f, 0.f, 0.f, 0.f};
        mfma16(S, kf0, qf[0]);
        mfma16(S, kf1, qf[1]);
        f32x4 k2v = *(const f32x4*)&k2buf[bb][jt * 16 + (g << 2)];
        f32x4 pr;
        #pragma unroll
        for (int r = 0; r < 4; ++r)
          pr[r] = __builtin_amdgcn_exp2f(fmaf(S[r], CQK, -k2v[r]));
        __hip_bfloat162 lo = __float22bfloat162_rn(make_float2(pr[0], pr[1]));
        __hip_bfloat162 hi = __float22bfloat162_rn(make_float2(pr[2], pr[3]));
        unsigned lo_u, hi_u;
        __builtin_memcpy(&lo_u, &lo, 4);
        __builtin_memcpy(&hi_u, &hi, 4);
        u32x2 pk;
        pk[0] = lo_u;
        pk[1] = hi_u;
        *(u32x2*)(Pw + i * 80 + t * 32 + g * 8) = pk;   // row q=i, j-local t*16+g*4..+3
      }
      short8 pf = *(const short8*)(Pw + i * 80 + g * 16);  // A-frag: row i, k = g*8..+7
      mfma16(accden, pf, ONES);
      #pragma unroll
      for (int ds = 0; ds < 4; ++ds) {
        const int vrow = ds * 16 + i;
        const int c = u * 4 + g;
        short8 vf = *(const short8*)(Vb + (vrow << 7) + ((c ^ (vrow & 7)) << 4));
        mfma16(acc[ds], pf, vf);
      }
    }
    __syncthreads();
  }

  float linv[4];
  #pragma unroll
  for (int r = 0; r < 4; ++r) linv[r] = 1.0f / accden[r];
  #pragma unroll
  for (int ds = 0; ds < 4; ++ds)
    #pragma unroll
    for (int r = 0; r < 4; ++r) {
      int row = qbase + (g << 2) + r;
      ctx[(size_t)(b * 4096 + row) * 512 + h * 64 + ds * 16 + i] =
          f2bf(acc[ds][r] * linv[r]);
    }
}

// ---------------- final expmap0 over 512-dim rows ----------------
__global__ __launch_bounds__(256) void final_kernel(const float* xin, float* out) {
  const int row = blockIdx.x;
  const int tid = threadIdx.x;
  const float* xr = xin + (size_t)row * 512;
  float v0 = xr[tid], v1 = xr[tid + 256];
  float ss = v0 * v0 + v1 * v1;
  #pragma unroll
  for (int m = 1; m <= 32; m <<= 1) ss += __shfl_xor(ss, m, 64);
  __shared__ __align__(16) float red[4];
  if ((tid & 63) == 0) red[tid >> 6] = ss;
  __syncthreads();
  float tot = (red[0] + red[1]) + (red[2] + red[3]);
  float n = fmaxf(sqrtf(tot), 1e-7f);
  float sc = tanhf(n) / n;
  out[(size_t)row * 512 + tid] = v0 * sc;
  out[(size_t)row * 512 + tid + 256] = v1 * sc;
}

// ---------------- launch ----------------
extern "C" void kernel_launch(void* const* d_in, const int* in_sizes, int n_in,
                              void* d_out, int out_size, void* d_ws, size_t ws_size,
                              hipStream_t stream) {
  const float* inputs = (const float*)d_in[0];
  const float* Wq = (const float*)d_in[1];
  const float* Wk = (const float*)d_in[2];
  const float* Wv = (const float*)d_in[3];
  const float* Wo = (const float*)d_in[4];
  float* out = (float*)d_out;
  char* ws = (char*)d_ws;

  // workspace layout (~79.25 MB peak):
  //  [0,48M):  qkv f32 [8192][1536]  -- reused after hyp: ctx bf16 @0 (8M), out_pre f32 @8M (16M)
  //  [48M):    tangent bf16 (4M)     -- reused after proj: k2lT f32 (256K)
  //  [53M): wqkvT bf16 (0.75M); [54M): woT bf16 (0.5M)
  //  [55M): qh bf16 (8M); [63M): kh bf16 (8M); [71M): vT bf16 (8M)
  float* qkv            = (float*)(ws);
  unsigned short* ctx   = (unsigned short*)(ws);
  float* out_pre        = (float*)(ws + ((size_t)8 << 20));
  unsigned short* tang  = (unsigned short*)(ws + ((size_t)48 << 20));
  float* k2lT           = (float*)(ws + ((size_t)48 << 20));
  unsigned short* wqkvT = (unsigned short*)(ws + ((size_t)53 << 20));
  unsigned short* woT   = (unsigned short*)(ws + ((size_t)54 << 20));
  unsigned short* qh    = (unsigned short*)(ws + ((size_t)55 << 20));
  unsigned short* kh    = (unsigned short*)(ws + ((size_t)63 << 20));
  unsigned short* vT    = (unsigned short*)(ws + ((size_t)71 << 20));

  wconv_kernel<<<2560, 256, 0, stream>>>(Wq, Wk, Wv, Wo, wqkvT, woT);
  tangent_kernel<<<8192, 256, 0, stream>>>(inputs, tang);
  gemm_bt<<<128 * 24, 256, 0, stream>>>(tang, wqkvT, qkv, 8192, 1536, 256, 24);
  hyp_kernel<<<1024, 256, 0, stream>>>(qkv, qh, kh, vT, k2lT);
  attn_kernel<<<512, 512, 0, stream>>>(qh, kh, vT, k2lT, ctx);
  gemm_bt<<<128 * 8, 256, 0, stream>>>(ctx, woT, out_pre, 8192, 512, 512, 8);
  final_kernel<<<8192, 256, 0, stream>>>(out_pre, out);
}